// Round 9
// baseline (200.676 us; speedup 1.0000x reference)
//
#include <hip/hip_runtime.h>
#include <hip/hip_bf16.h>
#include <math.h>

// ---------------------------------------------------------------------------
// Round 16: r10's 4-wave split-weight pipeline at NATURAL register pressure.
// Evidence: all 2-wave variants land 114-122us (r8/r12/r13/r15) -- exposed
// latency at 2 waves/SIMD (hidden AGPR weights => ~250 total regs/wave).
// r10's spill was the launch_bounds(256,3) HARD CAP (170) forcing an ~84/84
// arch/accum split; the unconstrained bound-2 version was never tried.
// This round: identical r10 dataflow, __launch_bounds__(256,2), natural
// allocation ~64 accum (half-weights) + ~90-105 arch ~= 155-170 total =>
// runtime occupancy 512/regs = 3 waves/SIMD WITHOUT a forcing cap.
//   + r13 refinements: fp32 LDS bias tables (C-init via ds_read, -8 arch),
//     single-shuffle L4 partial (xor 32 only; lane<32 -> vs, 13KB),
//     hshT overlaid on vs pool (prologue-only), asym setprio (P=0, C=1).
// Builtin MFMA only (r14: raw asm broke MFMA hazard handling).
// Structure verbatim r10 (proven correct, absmax 0.125): waves 0,1 = L2
// halves; waves 2,3 = L3 halves + L4; distributed Y1 build (each wave its
// kk=w slice), y1x/y2x double buffers, TPB+1 matched barriers per role.
// ---------------------------------------------------------------------------

#define B_N    16384
#define KQ     51
#define HD     128
#define IND    64
#define BLK    256               // 4 waves
#define RPB    16                // b-rows per block
#define GRID   (B_N / RPB)       // 1024
#define TPB    ((RPB * KQ) / 16) // 51 tiles per block (exact)

typedef __attribute__((ext_vector_type(8))) short short8;
typedef __attribute__((ext_vector_type(4))) float f32x4;

union S8U { short8 s8; unsigned u[4]; };

__device__ __forceinline__ unsigned short f2bf(float f) {
    __hip_bfloat16 t = __float2bfloat16(f);
    return *reinterpret_cast<unsigned short*>(&t);
}

#if defined(__gfx950__) && defined(__has_builtin)
#if __has_builtin(__builtin_amdgcn_cvt_pk_bf16_f32)
#define HAVE_PK_BF16 1
#endif
#endif

__device__ __forceinline__ unsigned pk_bf16(float lo, float hi) {
#ifdef HAVE_PK_BF16
    typedef __attribute__((ext_vector_type(2))) __bf16 bfv2;
    bfv2 r = __builtin_amdgcn_cvt_pk_bf16_f32(lo, hi);
    return *reinterpret_cast<unsigned*>(&r);
#else
    return (unsigned)f2bf(lo) | ((unsigned)f2bf(hi) << 16);
#endif
}

__launch_bounds__(BLK, 2)
__global__ void umnn_fused(const float* __restrict__ x,  const float* __restrict__ h,
                           const float* __restrict__ W1, const float* __restrict__ b1,
                           const float* __restrict__ W2, const float* __restrict__ b2,
                           const float* __restrict__ W3, const float* __restrict__ b3,
                           const float* __restrict__ W4, const float* __restrict__ b4,
                           float* __restrict__ out)
{
    __shared__ __align__(16) float hpL[RPB * HD];      // 8 KB block hpart
    __shared__ __align__(16) char  y1x[2][4096];       // 8 KB Y1 double buffer
    __shared__ __align__(16) char  y2x[2][4096];       // 8 KB Y2 double buffer
    __shared__ __align__(16) float poolF[2 * TPB * 32];// 12.75 KB overlay:
                                                       //   prologue: hshT[63*20]
                                                       //   loop: vs half-partials
    __shared__ __align__(16) float b2f[HD], b3f[HD];   // 1 KB fp32 bias tables
    __shared__ float xL[RPB];
    __shared__ float sSteps[KQ], sCcw[KQ];
    __shared__ float red4[4];

    float* hshT = poolF;                               // prologue-only alias

    const int tid  = threadIdx.x;
    const int w    = tid >> 6;          // wave 0..3
    const int lane = tid & 63;
    const int q    = lane >> 4;
    const int lm   = lane & 15;
    const int swz  = lm & 7;
    const bool isL2 = (w < 2);
    const int ntB  = (w & 1) * 4;       // weight half: rows ntB*16 .. +63
    const int rowBase = blockIdx.x * RPB;

    // ---- CC tables (validated r4 formula) ----
    if (tid < KQ) {
        const int j = tid;
        const float pi50 = 0.06283185307179586f;
        sSteps[j] = __cosf((float)j * pi50);
        float s = 0.0f;
        for (int i = 0; i <= 50; i += 2) {
            float Wi = (i == 0) ? 1.0f : 2.0f / (1.0f - (float)(i * i));
            float lam;
            if (j == 0) lam = 0.5f;
            else {
                int mp = (i * j) % 100;
                lam = __cosf((float)mp * pi50);
                if (j == 50) lam *= 0.5f;
            }
            s += (lam * 0.04f) * Wi;
        }
        sCcw[j] = s;
    }
    // ---- fp32 bias tables ----
    if (tid < HD) {
        b2f[tid] = b2[tid];
        b3f[tid] = b3[tid];
    }

    // ---- hoisted weight-fragment loads (L2 latency under prologue) ----
    const float* Wsel = isL2 ? W2 : W3;
    short8 WA[4][4];
    #pragma unroll
    for (int nt = 0; nt < 4; ++nt) {
        #pragma unroll
        for (int kk = 0; kk < 4; ++kk) {
            const float* p = Wsel + ((ntB + nt) * 16 + lm) * HD + kk * 32 + q * 8;
            S8U a;
            #pragma unroll
            for (int j = 0; j < 4; ++j)
                a.u[j] = pk_bf16(p[2 * j], p[2 * j + 1]);
            WA[nt][kk] = a.s8;
        }
    }
    f32x4 W4c[4];
    if (!isL2) {
        #pragma unroll
        for (int nt = 0; nt < 4; ++nt)
            W4c[nt] = *(const f32x4*)(W4 + (ntB + nt) * 16 + q * 4);
    }
    const float b4v = b4[0];
    float w1x[8];                       // this wave's kk = w feature slice
    #pragma unroll
    for (int j = 0; j < 8; ++j)
        w1x[j] = W1[(w * 32 + q * 8 + j) * IND];

    // ---- xmax scan (x: 64 KB, cache-resident) ----
    {
        const f32x4* x4 = (const f32x4*)x;
        float mx = -1e30f;
        for (int i = tid; i < B_N / 4; i += BLK) {
            f32x4 v = x4[i];
            mx = fmaxf(fmaxf(mx, fmaxf(v[0], v[1])), fmaxf(v[2], v[3]));
        }
        #pragma unroll
        for (int d = 32; d > 0; d >>= 1) mx = fmaxf(mx, __shfl_xor(mx, d));
        if (lane == 0) red4[w] = mx;
    }
    // ---- stage h^T for this block's 16 rows; init xL ----
    for (int i = tid; i < RPB * 63; i += BLK) {
        int r = i / 63, d = i - r * 63;
        hshT[d * 20 + r] = h[rowBase * 63 + i];
    }
    if (tid < RPB) xL[tid] = x[rowBase + tid];
    __syncthreads();                                   // B1

    const float xmax = fmaxf(fmaxf(red4[0], red4[1]),
                             fmaxf(red4[2], red4[3])) + 10.0f;

    // ---- block hpart: thread = feature (tid&127), 8 rows per half ----
    {
        const int n  = tid & 127;
        const int rh = (tid >> 7) * 8;  // rows rh..rh+7
        float acc[8];
        const float b1v = b1[n];
        #pragma unroll
        for (int r = 0; r < 8; ++r) acc[r] = b1v;
        const float* wr = W1 + n * IND + 1;
        #pragma unroll 1
        for (int d = 0; d < IND - 1; ++d) {
            float wv = wr[d];
            const float* ht = hshT + d * 20 + rh;
            f32x4 hv0 = *(const f32x4*)ht;
            f32x4 hv1 = *(const f32x4*)(ht + 4);
            acc[0] = fmaf(wv, hv0[0], acc[0]);
            acc[1] = fmaf(wv, hv0[1], acc[1]);
            acc[2] = fmaf(wv, hv0[2], acc[2]);
            acc[3] = fmaf(wv, hv0[3], acc[3]);
            acc[4] = fmaf(wv, hv1[0], acc[4]);
            acc[5] = fmaf(wv, hv1[1], acc[5]);
            acc[6] = fmaf(wv, hv1[2], acc[6]);
            acc[7] = fmaf(wv, hv1[3], acc[7]);
        }
        #pragma unroll
        for (int r = 0; r < 8; ++r) hpL[(rh + r) * HD + n] = acc[r];
    }
    __syncthreads();                                   // B2 (hpL ready; hshT dead)

    // ---- per-lane constant LDS offsets (layout math verbatim from r10) ----
    int rdOff[4];                                      // full-frag read (Y1/Y2)
    #pragma unroll
    for (int kk = 0; kk < 4; ++kk)
        rdOff[kk] = lm * 256 + (((kk * 4 + q) ^ swz) << 4);
    const int bldOff = lm * 256 + (((w * 4 + q) ^ swz) << 4);
    // C-init byte offset into bias table: feature (ntB+nt)*16 + q*4
    const int bIoff = ntB * 64 + q * 16;               // + nt*64 at use site

    // Y1 builder: this wave contributes kk = w (features w*32 .. w*32+31)
    auto buildY1 = [&](int ib, char* dst) {
        const int s   = ib * 16 + lm;          // 0..815 (guarded: never 816+)
        const int row = s / KQ;                // 0..15
        const int k   = s - row * KQ;          // 0..50
        const float x0 = xL[row];
        const float X  = fmaf((xmax - x0) * 0.5f, sSteps[k] + 1.0f, x0);
        const float* hp = hpL + row * HD + w * 32 + q * 8;
        f32x4 ha = *(const f32x4*)hp;
        f32x4 hb = *(const f32x4*)(hp + 4);
        S8U u;
        u.u[0] = pk_bf16(fmaxf(fmaf(X, w1x[0], ha[0]), 0.f),
                         fmaxf(fmaf(X, w1x[1], ha[1]), 0.f));
        u.u[1] = pk_bf16(fmaxf(fmaf(X, w1x[2], ha[2]), 0.f),
                         fmaxf(fmaf(X, w1x[3], ha[3]), 0.f));
        u.u[2] = pk_bf16(fmaxf(fmaf(X, w1x[4], hb[0]), 0.f),
                         fmaxf(fmaf(X, w1x[5], hb[1]), 0.f));
        u.u[3] = pk_bf16(fmaxf(fmaf(X, w1x[6], hb[2]), 0.f),
                         fmaxf(fmaf(X, w1x[7], hb[3]), 0.f));
        *(short8*)(dst + bldOff) = u.s8;
    };

    // prologue: all 4 waves build their slice of tile 0
    buildY1(0, y1x[0]);
    __syncthreads();                                   // B3

    if (isL2) {
        // =============== PRODUCER loop: TPB iters + 1 match-barrier ========
        __builtin_amdgcn_s_setprio(0);
        int wrOff[4];
        #pragma unroll
        for (int nt = 0; nt < 4; ++nt)
            wrOff[nt] = lm * 256 + (((2 * (ntB + nt) + (q >> 1)) ^ swz) << 4)
                      + ((q & 1) << 3);
        const char* bC = (const char*)b2f;
        #pragma unroll 1
        for (int j = 0; j < TPB; ++j) {
            const char* src = y1x[j & 1];
            short8 Yf[4];
            #pragma unroll
            for (int kk = 0; kk < 4; ++kk)
                Yf[kk] = *(const short8*)(src + rdOff[kk]);

            f32x4 C[4];
            #pragma unroll
            for (int nt = 0; nt < 4; ++nt)
                C[nt] = *(const f32x4*)(bC + nt * 64 + bIoff);
            #pragma unroll
            for (int kk = 0; kk < 4; ++kk)
                #pragma unroll
                for (int nt = 0; nt < 4; ++nt)
                    C[nt] = __builtin_amdgcn_mfma_f32_16x16x32_bf16(WA[nt][kk], Yf[kk], C[nt], 0, 0, 0);

            char* d2 = y2x[j & 1];
            #pragma unroll
            for (int nt = 0; nt < 4; ++nt) {
                unsigned lo = pk_bf16(fmaxf(C[nt][0], 0.f), fmaxf(C[nt][1], 0.f));
                unsigned hi = pk_bf16(fmaxf(C[nt][2], 0.f), fmaxf(C[nt][3], 0.f));
                *(int2*)(d2 + wrOff[nt]) = make_int2((int)lo, (int)hi);
            }
            if (j + 1 < TPB) buildY1(j + 1, y1x[(j + 1) & 1]);
            __syncthreads();                           // barrier j+1
        }
        __syncthreads();                               // match consumer tail
    } else {
        // =============== CONSUMER loop: lag-1, TPB iters + tail ===========
        __builtin_amdgcn_s_setprio(1);                 // consumer is critical
        float* vsW = poolF + (w & 1) * (TPB * 32);
        const char* bC = (const char*)b3f;

        // one full consume body (tile tt from parity buffer src)
        auto consume = [&](int tt, const char* src) {
            short8 Yf[4];
            #pragma unroll
            for (int kk = 0; kk < 4; ++kk)
                Yf[kk] = *(const short8*)(src + rdOff[kk]);
            f32x4 C[4];
            #pragma unroll
            for (int nt = 0; nt < 4; ++nt)
                C[nt] = *(const f32x4*)(bC + nt * 64 + bIoff);
            #pragma unroll
            for (int kk = 0; kk < 4; ++kk)
                #pragma unroll
                for (int nt = 0; nt < 4; ++nt)
                    C[nt] = __builtin_amdgcn_mfma_f32_16x16x32_bf16(WA[nt][kk], Yf[kk], C[nt], 0, 0, 0);
            float pa = 0.f;
            #pragma unroll
            for (int nt = 0; nt < 4; ++nt) {
                pa = fmaf(fmaxf(C[nt][0], 0.f), W4c[nt][0], pa);
                pa = fmaf(fmaxf(C[nt][1], 0.f), W4c[nt][1], pa);
                pa = fmaf(fmaxf(C[nt][2], 0.f), W4c[nt][2], pa);
                pa = fmaf(fmaxf(C[nt][3], 0.f), W4c[nt][3], pa);
            }
            pa += __shfl_xor(pa, 32);                  // single shuffle
            if (lane < 32) vsW[tt * 32 + lane] = pa;   // 2 partials/sample
        };

        // j = 0: nothing to consume yet; build tile 1
        buildY1(1, y1x[1]);
        __syncthreads();                               // barrier 1
        #pragma unroll 1
        for (int j = 1; j < TPB; ++j) {
            consume(j - 1, y2x[(j - 1) & 1]);
            if (j + 1 < TPB) buildY1(j + 1, y1x[(j + 1) & 1]);
            __syncthreads();                           // barrier j+1
        }
        consume(TPB - 1, y2x[(TPB - 1) & 1]);          // tail
        __syncthreads();                               // final barrier
    }

    // ---- deferred epilogue (wave 0, after all barriers line up) ----
    if (w == 0) {
        const float* vs0 = poolF;
        const float* vs1 = poolF + TPB * 32;
        const int r   = lane >> 2;                     // row 0..15
        const int sub = lane & 3;
        float a = 0.f;
        #pragma unroll 1
        for (int j = 0; j < 13; ++j) {
            int k = sub + 4 * j;
            if (k < KQ) {
                int s   = r * KQ + k;
                int tt  = s >> 4;
                int lm2 = s & 15;
                float y4 = vs0[tt * 32 + lm2] + vs0[tt * 32 + 16 + lm2]
                         + vs1[tt * 32 + lm2] + vs1[tt * 32 + 16 + lm2] + b4v;
                float f  = (y4 > 0.f) ? (y4 + 1.f) : __expf(y4);
                a = fmaf(f, sCcw[k], a);
            }
        }
        a += __shfl_xor(a, 1);
        a += __shfl_xor(a, 2);
        if (sub == 0)
            out[rowBase + r] = a * (xmax - xL[r]) * 0.5f;
    }
}

// ---------------------------------------------------------------------------
extern "C" void kernel_launch(void* const* d_in, const int* in_sizes, int n_in,
                              void* d_out, int out_size, void* d_ws, size_t ws_size,
                              hipStream_t stream)
{
    const float* x  = (const float*)d_in[0];
    const float* h  = (const float*)d_in[1];
    const float* W1 = (const float*)d_in[2];
    const float* b1 = (const float*)d_in[3];
    const float* W2 = (const float*)d_in[4];
    const float* b2 = (const float*)d_in[5];
    const float* W3 = (const float*)d_in[6];
    const float* b3 = (const float*)d_in[7];
    const float* W4 = (const float*)d_in[8];
    const float* b4 = (const float*)d_in[9];
    float* out = (float*)d_out;

    umnn_fused<<<GRID, BLK, 0, stream>>>(x, h, W1, b1, W2, b2, W3, b3,
                                         W4, b4, out);
}

// Round 10
// 177.266 us; speedup vs baseline: 1.1321x; 1.1321x over previous
//
#include <hip/hip_runtime.h>
#include <hip/hip_bf16.h>
#include <math.h>

// ---------------------------------------------------------------------------
// Round 17: r13 (best known good: 114us) with the loop BARRIERS REMOVED.
// Evidence r8-r16: all barrier-phased 2-wave variants land 114-122us with
// ~5.4K cyc/phase vs ~1-2K of issue work; r15 ruled out barrier COUNT,
// r12/r13 ruled out chain length. Remaining theory: the shared per-phase
// barrier CORRELATES P and C stalls (both waves bubble at the same instants
// => neither covers the other). Fix: flag-based P/C sync, 4-slot Y2 ring:
//   producer: wait (tt - ccnt < 4) -> produce slot tt&3 -> release-store
//             pcnt=tt+1 (forces lgkmcnt(0) drain of Y2 writes)
//   consumer: acquire-spin pcnt>tt -> consume slot -> release-store ccnt
//   spins use s_sleep (wave off issue port); counters monotone <=51.
// Slots 2,3 overlay prologue-only hshT (alias) => LDS ~39.1KB, still 4
// blocks/CU. Bodies/swizzles/vs4/bias-tables/asym-setprio verbatim r13.
// Numerics: identical chain to r13; absmax ~0.125 vs thr 0.4725.
// ---------------------------------------------------------------------------

#define B_N    16384
#define KQ     51
#define HD     128
#define IND    64
#define BLK    128               // 2 waves: producer + consumer
#define RPB    16                // b-rows per block
#define GRID   (B_N / RPB)       // 1024
#define TPB    ((RPB * KQ) / 16) // 51 tiles per block (exact)
#define NSLOT  4                 // Y2 ring depth

typedef __attribute__((ext_vector_type(8))) short short8;
typedef __attribute__((ext_vector_type(4))) float f32x4;

union S8U { short8 s8; unsigned u[4]; };

__device__ __forceinline__ unsigned short f2bf(float f) {
    __hip_bfloat16 t = __float2bfloat16(f);
    return *reinterpret_cast<unsigned short*>(&t);
}

#if defined(__gfx950__) && defined(__has_builtin)
#if __has_builtin(__builtin_amdgcn_cvt_pk_bf16_f32)
#define HAVE_PK_BF16 1
#endif
#endif

__device__ __forceinline__ unsigned pk_bf16(float lo, float hi) {
#ifdef HAVE_PK_BF16
    typedef __attribute__((ext_vector_type(2))) __bf16 bfv2;
    bfv2 r = __builtin_amdgcn_cvt_pk_bf16_f32(lo, hi);
    return *reinterpret_cast<unsigned*>(&r);
#else
    return (unsigned)f2bf(lo) | ((unsigned)f2bf(hi) << 16);
#endif
}

__launch_bounds__(BLK, 2)
__global__ void umnn_fused(const float* __restrict__ x,  const float* __restrict__ h,
                           const float* __restrict__ W1, const float* __restrict__ b1,
                           const float* __restrict__ W2, const float* __restrict__ b2,
                           const float* __restrict__ W3, const float* __restrict__ b3,
                           const float* __restrict__ W4, const float* __restrict__ b4,
                           float* __restrict__ out)
{
    __shared__ __align__(16) float hpL[RPB * HD];      // 8 KB block hpart
    __shared__ __align__(16) char  y2all[NSLOT][4096]; // 16 KB Y2 ring
                                                       //   slots 2,3 overlay
                                                       //   prologue hshT (5KB)
    __shared__ __align__(16) float vs4[TPB * 64];      // 12.75 KB per-lane partials
    __shared__ __align__(16) float b2f[HD], b3f[HD];   // 1 KB fp32 bias tables
    __shared__ float xL[RPB];
    __shared__ float sSteps[KQ], sCcw[KQ];
    __shared__ float red2[2];
    __shared__ int   pcnt, ccnt;                       // P/C progress flags

    float* hshT = (float*)y2all[2];                    // prologue-only alias

    const int tid  = threadIdx.x;
    const int w    = tid >> 6;
    const int lane = tid & 63;
    const int q    = lane >> 4;
    const int lm   = lane & 15;
    const int swz  = lm & 7;
    const int rowBase = blockIdx.x * RPB;

    if (tid == 0) { pcnt = 0; ccnt = 0; }

    // ---- CC tables (validated r4 formula) ----
    if (tid < KQ) {
        const int j = tid;
        const float pi50 = 0.06283185307179586f;
        sSteps[j] = __cosf((float)j * pi50);
        float s = 0.0f;
        for (int i = 0; i <= 50; i += 2) {
            float Wi = (i == 0) ? 1.0f : 2.0f / (1.0f - (float)(i * i));
            float lam;
            if (j == 0) lam = 0.5f;
            else {
                int mp = (i * j) % 100;
                lam = __cosf((float)mp * pi50);
                if (j == 50) lam *= 0.5f;
            }
            s += (lam * 0.04f) * Wi;
        }
        sCcw[j] = s;
    }
    // ---- fp32 bias tables ----
    if (tid < HD) {
        b2f[tid] = b2[tid];
        b3f[tid] = b3[tid];
    }
    // ---- xmax scan (x: 64 KB, cache-resident) ----
    {
        const f32x4* x4 = (const f32x4*)x;
        float mx = -1e30f;
        for (int i = tid; i < B_N / 4; i += BLK) {
            f32x4 v = x4[i];
            mx = fmaxf(fmaxf(mx, fmaxf(v[0], v[1])), fmaxf(v[2], v[3]));
        }
        #pragma unroll
        for (int d = 32; d > 0; d >>= 1) mx = fmaxf(mx, __shfl_xor(mx, d));
        if (lane == 0) red2[w] = mx;
    }
    // ---- stage h^T for this block's 16 rows; init xL ----
    for (int i = tid; i < RPB * 63; i += BLK) {
        int r = i / 63, d = i - r * 63;
        hshT[d * 20 + r] = h[rowBase * 63 + i];
    }
    if (tid < RPB) xL[tid] = x[rowBase + tid];
    __syncthreads();                                   // B1

    const float xmax = fmaxf(red2[0], red2[1]) + 10.0f;

    // ---- block hpart: thread tid = feature n, 16 row-accumulators ----
    {
        const int n = tid;
        float acc[RPB];
        const float b1v = b1[n];
        #pragma unroll
        for (int r = 0; r < RPB; ++r) acc[r] = b1v;
        const float* wr = W1 + n * IND + 1;
        #pragma unroll 1
        for (int d = 0; d < IND - 1; ++d) {
            float wv = wr[d];
            const float* ht = hshT + d * 20;
            #pragma unroll
            for (int rc = 0; rc < RPB / 4; ++rc) {
                f32x4 hv = *(const f32x4*)(ht + rc * 4);
                acc[rc * 4 + 0] = fmaf(wv, hv[0], acc[rc * 4 + 0]);
                acc[rc * 4 + 1] = fmaf(wv, hv[1], acc[rc * 4 + 1]);
                acc[rc * 4 + 2] = fmaf(wv, hv[2], acc[rc * 4 + 2]);
                acc[rc * 4 + 3] = fmaf(wv, hv[3], acc[rc * 4 + 3]);
            }
        }
        #pragma unroll
        for (int r = 0; r < RPB; ++r) hpL[r * HD + n] = acc[r];
    }
    __syncthreads();                                   // B2 (hpL ready; hshT dead)

    // per-lane C-init byte offset into bias table: feature nt*16+q*4
    const int bIoff = q * 16;                          // + nt*64 at use site

    if (w == 0) {
        // ================= PRODUCER: layer 1 + layer 2 =================
        __builtin_amdgcn_s_setprio(0);
        float w1x[32];
        #pragma unroll
        for (int kk = 0; kk < 4; ++kk)
            #pragma unroll
            for (int j = 0; j < 8; ++j)
                w1x[kk * 8 + j] = W1[(kk * 32 + q * 8 + j) * IND];

        short8 W2A[8][4];
        #pragma unroll
        for (int nt = 0; nt < 8; ++nt) {
            #pragma unroll
            for (int kk = 0; kk < 4; ++kk) {
                const float* p2 = W2 + (nt * 16 + lm) * HD + kk * 32 + q * 8;
                S8U a2;
                #pragma unroll
                for (int j = 0; j < 4; ++j)
                    a2.u[j] = pk_bf16(p2[2 * j], p2[2 * j + 1]);
                W2A[nt][kk] = a2.s8;
            }
        }
        int wrOff[8];
        #pragma unroll
        for (int nt = 0; nt < 8; ++nt)
            wrOff[nt] = lm * 256 + (((2 * nt + (q >> 1)) ^ swz) << 4) + ((q & 1) << 3);
        const char* b2c = (const char*)b2f;

        #pragma unroll 1
        for (int tt = 0; tt < TPB; ++tt) {
            // ---- wait for ring space (consumer >= tt-3 done) ----
            while (tt - __hip_atomic_load(&ccnt, __ATOMIC_ACQUIRE,
                                          __HIP_MEMORY_SCOPE_WORKGROUP) >= NSLOT)
                __builtin_amdgcn_s_sleep(1);

            // ---- layer 1: build Y1 fragment for this tile ----
            const int s    = tt * 16 + lm;             // 0..815
            const unsigned row = (unsigned)s / KQ;     // 0..15
            const int k    = s - (int)row * KQ;
            const float x0 = xL[row];
            const float X  = fmaf((xmax - x0) * 0.5f, sSteps[k] + 1.0f, x0);
            short8 Y1[4];
            #pragma unroll
            for (int kk = 0; kk < 4; ++kk) {
                const float* hp = hpL + row * HD + kk * 32 + q * 8;
                f32x4 ha = *(const f32x4*)hp;
                f32x4 hb = *(const f32x4*)(hp + 4);
                S8U u;
                u.u[0] = pk_bf16(fmaxf(fmaf(X, w1x[kk*8+0], ha[0]), 0.f),
                                 fmaxf(fmaf(X, w1x[kk*8+1], ha[1]), 0.f));
                u.u[1] = pk_bf16(fmaxf(fmaf(X, w1x[kk*8+2], ha[2]), 0.f),
                                 fmaxf(fmaf(X, w1x[kk*8+3], ha[3]), 0.f));
                u.u[2] = pk_bf16(fmaxf(fmaf(X, w1x[kk*8+4], hb[0]), 0.f),
                                 fmaxf(fmaf(X, w1x[kk*8+5], hb[1]), 0.f));
                u.u[3] = pk_bf16(fmaxf(fmaf(X, w1x[kk*8+6], hb[2]), 0.f),
                                 fmaxf(fmaf(X, w1x[kk*8+7], hb[3]), 0.f));
                Y1[kk] = u.s8;
            }

            // ---- layer 2: C init from LDS bias table, 32 MFMA ----
            f32x4 C[8];
            #pragma unroll
            for (int nt = 0; nt < 8; ++nt)
                C[nt] = *(const f32x4*)(b2c + nt * 64 + bIoff);
            #pragma unroll
            for (int kk = 0; kk < 4; ++kk)
                #pragma unroll
                for (int nt = 0; nt < 8; ++nt)
                    C[nt] = __builtin_amdgcn_mfma_f32_16x16x32_bf16(W2A[nt][kk], Y1[kk], C[nt], 0, 0, 0);

            // ---- relu + pack + write Y2 slot ----
            char* d2 = y2all[tt & (NSLOT - 1)];
            #pragma unroll
            for (int nt = 0; nt < 8; ++nt) {
                unsigned lo = pk_bf16(fmaxf(C[nt][0], 0.f), fmaxf(C[nt][1], 0.f));
                unsigned hi = pk_bf16(fmaxf(C[nt][2], 0.f), fmaxf(C[nt][3], 0.f));
                *(int2*)(d2 + wrOff[nt]) = make_int2((int)lo, (int)hi);
            }
            // ---- publish tile tt (release drains Y2 writes) ----
            if (lane == 0)
                __hip_atomic_store(&pcnt, tt + 1, __ATOMIC_RELEASE,
                                   __HIP_MEMORY_SCOPE_WORKGROUP);
        }
    } else {
        // ================= CONSUMER: layer 3 + layer 4 =================
        __builtin_amdgcn_s_setprio(1);                 // consumer is critical
        short8 W3A[8][4];
        f32x4  W4c[8];
        #pragma unroll
        for (int nt = 0; nt < 8; ++nt) {
            #pragma unroll
            for (int kk = 0; kk < 4; ++kk) {
                const float* p3 = W3 + (nt * 16 + lm) * HD + kk * 32 + q * 8;
                S8U a3;
                #pragma unroll
                for (int j = 0; j < 4; ++j)
                    a3.u[j] = pk_bf16(p3[2 * j], p3[2 * j + 1]);
                W3A[nt][kk] = a3.s8;
            }
            W4c[nt] = *(const f32x4*)(W4 + nt * 16 + q * 4);
        }
        const float b4v = b4[0];
        int rdOff[4];
        #pragma unroll
        for (int kk = 0; kk < 4; ++kk)
            rdOff[kk] = lm * 256 + (((kk * 4 + q) ^ swz) << 4);
        const char* b3c = (const char*)b3f;

        #pragma unroll 1
        for (int tt = 0; tt < TPB; ++tt) {
            // ---- wait for tile tt (acquire orders subsequent reads) ----
            while (__hip_atomic_load(&pcnt, __ATOMIC_ACQUIRE,
                                     __HIP_MEMORY_SCOPE_WORKGROUP) < tt + 1)
                __builtin_amdgcn_s_sleep(1);

            const char* s2 = y2all[tt & (NSLOT - 1)];
            short8 Y2[4];
            #pragma unroll
            for (int kk = 0; kk < 4; ++kk)
                Y2[kk] = *(const short8*)(s2 + rdOff[kk]);
            f32x4 C[8];
            #pragma unroll
            for (int nt = 0; nt < 8; ++nt)
                C[nt] = *(const f32x4*)(b3c + nt * 64 + bIoff);

            #pragma unroll
            for (int kk = 0; kk < 4; ++kk)
                #pragma unroll
                for (int nt = 0; nt < 8; ++nt)
                    C[nt] = __builtin_amdgcn_mfma_f32_16x16x32_bf16(W3A[nt][kk], Y2[kk], C[nt], 0, 0, 0);

            // ---- layer 4 per-lane partial: straight to LDS ----
            float p = 0.f;
            #pragma unroll
            for (int nt = 0; nt < 8; ++nt) {
                p = fmaf(fmaxf(C[nt][0], 0.f), W4c[nt][0], p);
                p = fmaf(fmaxf(C[nt][1], 0.f), W4c[nt][1], p);
                p = fmaf(fmaxf(C[nt][2], 0.f), W4c[nt][2], p);
                p = fmaf(fmaxf(C[nt][3], 0.f), W4c[nt][3], p);
            }
            vs4[tt * 64 + lane] = p;                   // conflict-free

            // ---- release slot (drains Y2 reads first) ----
            if (lane == 0)
                __hip_atomic_store(&ccnt, tt + 1, __ATOMIC_RELEASE,
                                   __HIP_MEMORY_SCOPE_WORKGROUP);
        }

        // ---- deferred epilogue: 4-way quarter sum + elu + ccw + reduce ----
        {
            const int r   = lane >> 2;                 // row 0..15
            const int sub = lane & 3;
            float a = 0.f;
            #pragma unroll 1
            for (int j = 0; j < 13; ++j) {
                int k = sub + 4 * j;
                if (k < KQ) {
                    int s   = r * KQ + k;
                    int tt  = s >> 4;
                    int lm2 = s & 15;
                    const float* vb = vs4 + tt * 64 + lm2;
                    float y4 = vb[0] + vb[16] + vb[32] + vb[48] + b4v;
                    float f  = (y4 > 0.f) ? (y4 + 1.f) : __expf(y4);
                    a = fmaf(f, sCcw[k], a);
                }
            }
            a += __shfl_xor(a, 1);
            a += __shfl_xor(a, 2);
            if (sub == 0)
                out[rowBase + r] = a * (xmax - xL[r]) * 0.5f;
        }
    }
}

// ---------------------------------------------------------------------------
extern "C" void kernel_launch(void* const* d_in, const int* in_sizes, int n_in,
                              void* d_out, int out_size, void* d_ws, size_t ws_size,
                              hipStream_t stream)
{
    const float* x  = (const float*)d_in[0];
    const float* h  = (const float*)d_in[1];
    const float* W1 = (const float*)d_in[2];
    const float* b1 = (const float*)d_in[3];
    const float* W2 = (const float*)d_in[4];
    const float* b2 = (const float*)d_in[5];
    const float* W3 = (const float*)d_in[6];
    const float* b3 = (const float*)d_in[7];
    const float* W4 = (const float*)d_in[8];
    const float* b4 = (const float*)d_in[9];
    float* out = (float*)d_out;

    umnn_fused<<<GRID, BLK, 0, stream>>>(x, h, W1, b1, W2, b2, W3, b3,
                                         W4, b4, out);
}

// Round 11
// 175.712 us; speedup vs baseline: 1.1421x; 1.0088x over previous
//
#include <hip/hip_runtime.h>
#include <hip/hip_bf16.h>
#include <math.h>

// ---------------------------------------------------------------------------
// Round 18: r13 skeleton (best: 114us) + L1 MOVED TO THE MATRIX PIPE.
// Sync-topology sweep complete (r13 114 / r15 119 / r17 125 / r16 144):
// sync is not the limiter. Counters: VALUBusy ~37 = 2x MfmaUtil ~18 in every
// variant -> VALU is the loaded pipe; biggest block = producer Y1-build
// (L1 on VALU, ~130 serial instr/tile) + 2.5K-cyc hpart prologue.
// Change: Y1 = relu([X|h] @ W1^T + b1) via 16 MFMA/tile (K=64, 2kk x 8nt),
// SAME A=weights/B=samples orientation as L2/L3 -> output layout identical
// to Y2 -> reuse the PROVEN pack/write+read swizzle pair for an
// intra-producer Y1 roundtrip (single buffer, same-wave ordering).
//   - xh B-frags: hbf[16][64] bf16 row table (2 ds_read_b128) + 3-op X
//     insert into element 0 (only kk=0,q=0 holds feature 0)
//   - W1 A-frags: 16KB LDS table, slot^=(n&7) XOR -> 2-way banks (free);
//     16 ds_read_b128/tile keeps producer regs ~220 (no new pressure)
//   - hpart/hshT/hpL prologue DELETED (folded into L1 MFMA)
//   - consumer: r13 verbatim + r16-proven single-shuffle vs2 (LDS diet
//     -> 39.3KB, 4 blocks/CU preserved)
// NUMERICS CHANGE (flagged): h/X/W1 round to bf16 pre-L1 (hpart was fp32).
// Est. absmax 0.2-0.3 vs thr 0.4725. Fallback if fail: fp32 X-term hybrid.
// ---------------------------------------------------------------------------

#define B_N    16384
#define KQ     51
#define HD     128
#define IND    64
#define BLK    128               // 2 waves: producer + consumer
#define RPB    16                // b-rows per block
#define GRID   (B_N / RPB)       // 1024
#define TPB    ((RPB * KQ) / 16) // 51 tiles per block (exact)

typedef __attribute__((ext_vector_type(8))) short short8;
typedef __attribute__((ext_vector_type(4))) float f32x4;

union S8U { short8 s8; unsigned u[4]; };

__device__ __forceinline__ unsigned short f2bf(float f) {
    __hip_bfloat16 t = __float2bfloat16(f);
    return *reinterpret_cast<unsigned short*>(&t);
}

#if defined(__gfx950__) && defined(__has_builtin)
#if __has_builtin(__builtin_amdgcn_cvt_pk_bf16_f32)
#define HAVE_PK_BF16 1
#endif
#endif

__device__ __forceinline__ unsigned pk_bf16(float lo, float hi) {
#ifdef HAVE_PK_BF16
    typedef __attribute__((ext_vector_type(2))) __bf16 bfv2;
    bfv2 r = __builtin_amdgcn_cvt_pk_bf16_f32(lo, hi);
    return *reinterpret_cast<unsigned*>(&r);
#else
    return (unsigned)f2bf(lo) | ((unsigned)f2bf(hi) << 16);
#endif
}

__launch_bounds__(BLK, 2)
__global__ void umnn_fused(const float* __restrict__ x,  const float* __restrict__ h,
                           const float* __restrict__ W1, const float* __restrict__ b1,
                           const float* __restrict__ W2, const float* __restrict__ b2,
                           const float* __restrict__ W3, const float* __restrict__ b3,
                           const float* __restrict__ W4, const float* __restrict__ b4,
                           float* __restrict__ out)
{
    __shared__ __align__(16) char  w1t[HD * 128];      // 16 KB W1 bf16 frag table
    __shared__ __align__(16) char  hbf[RPB * 128];     // 2 KB per-row h bf16
    __shared__ __align__(16) char  y1s[4096];          // 4 KB Y1 roundtrip
    __shared__ __align__(16) char  y2x[2][4096];       // 8 KB Y2 double buffer
    __shared__ __align__(16) float vs2[TPB * 32];      // 6.4 KB L4 partials
    __shared__ __align__(16) float b1f[HD], b2f[HD], b3f[HD]; // 1.5 KB biases
    __shared__ float xL[RPB];
    __shared__ float sSteps[KQ], sCcw[KQ];
    __shared__ float red2[2];

    const int tid  = threadIdx.x;
    const int w    = tid >> 6;
    const int lane = tid & 63;
    const int q    = lane >> 4;
    const int lm   = lane & 15;
    const int swz  = lm & 7;
    const int rowBase = blockIdx.x * RPB;

    // ---- CC tables (validated r4 formula) ----
    if (tid < KQ) {
        const int j = tid;
        const float pi50 = 0.06283185307179586f;
        sSteps[j] = __cosf((float)j * pi50);
        float s = 0.0f;
        for (int i = 0; i <= 50; i += 2) {
            float Wi = (i == 0) ? 1.0f : 2.0f / (1.0f - (float)(i * i));
            float lam;
            if (j == 0) lam = 0.5f;
            else {
                int mp = (i * j) % 100;
                lam = __cosf((float)mp * pi50);
                if (j == 50) lam *= 0.5f;
            }
            s += (lam * 0.04f) * Wi;
        }
        sCcw[j] = s;
    }
    // ---- fp32 bias tables ----
    if (tid < HD) {
        b1f[tid] = b1[tid];
        b2f[tid] = b2[tid];
        b3f[tid] = b3[tid];
    }
    // ---- xmax scan (x: 64 KB, cache-resident) ----
    {
        const f32x4* x4 = (const f32x4*)x;
        float mx = -1e30f;
        for (int i = tid; i < B_N / 4; i += BLK) {
            f32x4 v = x4[i];
            mx = fmaxf(fmaxf(mx, fmaxf(v[0], v[1])), fmaxf(v[2], v[3]));
        }
        #pragma unroll
        for (int d = 32; d > 0; d >>= 1) mx = fmaxf(mx, __shfl_xor(mx, d));
        if (lane == 0) red2[w] = mx;
    }
    // ---- stage hbf: bf16 of h, feature d -> slot d+1 (slot 0 = X at use) ----
    {
        unsigned short* hb = (unsigned short*)hbf;
        for (int i = tid; i < RPB * 63; i += BLK) {
            int r = i / 63, d = i - r * 63;
            hb[r * 64 + d + 1] = f2bf(h[rowBase * 63 + i]);
        }
    }
    // ---- stage w1t: thread n packs W1 row n into 8 swizzled 16B slots ----
    {
        const int n = tid;                 // 0..127
        const float* wr = W1 + n * IND;
        #pragma unroll
        for (int sl = 0; sl < 8; ++sl) {
            int4 v;
            v.x = (int)pk_bf16(wr[sl * 8 + 0], wr[sl * 8 + 1]);
            v.y = (int)pk_bf16(wr[sl * 8 + 2], wr[sl * 8 + 3]);
            v.z = (int)pk_bf16(wr[sl * 8 + 4], wr[sl * 8 + 5]);
            v.w = (int)pk_bf16(wr[sl * 8 + 6], wr[sl * 8 + 7]);
            *(int4*)(w1t + n * 128 + ((sl ^ (n & 7)) << 4)) = v;
        }
    }
    if (tid < RPB) xL[tid] = x[rowBase + tid];
    __syncthreads();                                   // B1 (everything staged)

    const float xmax = fmaxf(red2[0], red2[1]) + 10.0f;

    // per-lane C-init byte offset into bias tables: feature nt*16+q*4
    const int bIoff = q * 16;                          // + nt*64 at use site
    // full-frag read offsets (Y1/Y2), proven pair
    int rdOff[4];
    #pragma unroll
    for (int kk = 0; kk < 4; ++kk)
        rdOff[kk] = lm * 256 + (((kk * 4 + q) ^ swz) << 4);

    if (w == 0) {
        // ========== PRODUCER: L1 (MFMA) + L2 (MFMA) ==========
        __builtin_amdgcn_s_setprio(0);
        short8 W2A[8][4];
        #pragma unroll
        for (int nt = 0; nt < 8; ++nt) {
            #pragma unroll
            for (int kk = 0; kk < 4; ++kk) {
                const float* p2 = W2 + (nt * 16 + lm) * HD + kk * 32 + q * 8;
                S8U a2;
                #pragma unroll
                for (int j = 0; j < 4; ++j)
                    a2.u[j] = pk_bf16(p2[2 * j], p2[2 * j + 1]);
                W2A[nt][kk] = a2.s8;
            }
        }
        int wrOff[8];
        #pragma unroll
        for (int nt = 0; nt < 8; ++nt)
            wrOff[nt] = lm * 256 + (((2 * nt + (q >> 1)) ^ swz) << 4) + ((q & 1) << 3);
        // W1 A-frag read offsets: row n = nt*16+lm, slot kk*4+q, XOR swz
        int rdW1[2];
        #pragma unroll
        for (int kk = 0; kk < 2; ++kk)
            rdW1[kk] = lm * 128 + (((kk * 4 + q) ^ swz) << 4);  // + nt*2048
        const char* b1c = (const char*)b1f;
        const char* b2c = (const char*)b2f;
        const int hOff = q * 16;                       // + row*128

        #pragma unroll 1
        for (int tt = 0; tt < TPB; ++tt) {
            // ---- per-sample X ----
            const int s    = tt * 16 + lm;             // 0..815
            const unsigned row = (unsigned)s / KQ;     // 0..15
            const int k    = s - (int)row * KQ;
            const float x0 = xL[row];
            const float X  = fmaf((xmax - x0) * 0.5f, sSteps[k] + 1.0f, x0);
            const unsigned xb = (unsigned)f2bf(X);

            // ---- xh B-fragments (2 kk): h table + X insert at feature 0 ----
            short8 XH[2];
            #pragma unroll
            for (int kk = 0; kk < 2; ++kk)
                XH[kk] = *(const short8*)(hbf + row * 128 + kk * 64 + hOff);
            {
                S8U u; u.s8 = XH[0];
                u.u[0] = (q == 0) ? ((u.u[0] & 0xffff0000u) | xb) : u.u[0];
                XH[0] = u.s8;
            }

            // ---- L1: C init from b1f, 16 MFMA (W1 frags from LDS) ----
            f32x4 C[8];
            #pragma unroll
            for (int nt = 0; nt < 8; ++nt)
                C[nt] = *(const f32x4*)(b1c + nt * 64 + bIoff);
            #pragma unroll
            for (int kk = 0; kk < 2; ++kk)
                #pragma unroll
                for (int nt = 0; nt < 8; ++nt) {
                    short8 W1f = *(const short8*)(w1t + nt * 2048 + rdW1[kk]);
                    C[nt] = __builtin_amdgcn_mfma_f32_16x16x32_bf16(W1f, XH[kk], C[nt], 0, 0, 0);
                }

            // ---- Y1: relu+pack -> y1s (proven Y2-style pair, same wave) ----
            #pragma unroll
            for (int nt = 0; nt < 8; ++nt) {
                unsigned lo = pk_bf16(fmaxf(C[nt][0], 0.f), fmaxf(C[nt][1], 0.f));
                unsigned hi = pk_bf16(fmaxf(C[nt][2], 0.f), fmaxf(C[nt][3], 0.f));
                *(int2*)(y1s + wrOff[nt]) = make_int2((int)lo, (int)hi);
            }
            short8 Y1[4];
            #pragma unroll
            for (int kk = 0; kk < 4; ++kk)
                Y1[kk] = *(const short8*)(y1s + rdOff[kk]);

            // ---- L2: C init from b2f, 32 MFMA ----
            #pragma unroll
            for (int nt = 0; nt < 8; ++nt)
                C[nt] = *(const f32x4*)(b2c + nt * 64 + bIoff);
            #pragma unroll
            for (int kk = 0; kk < 4; ++kk)
                #pragma unroll
                for (int nt = 0; nt < 8; ++nt)
                    C[nt] = __builtin_amdgcn_mfma_f32_16x16x32_bf16(W2A[nt][kk], Y1[kk], C[nt], 0, 0, 0);

            // ---- relu + pack + write Y2 ----
            char* d2 = y2x[tt & 1];
            #pragma unroll
            for (int nt = 0; nt < 8; ++nt) {
                unsigned lo = pk_bf16(fmaxf(C[nt][0], 0.f), fmaxf(C[nt][1], 0.f));
                unsigned hi = pk_bf16(fmaxf(C[nt][2], 0.f), fmaxf(C[nt][3], 0.f));
                *(int2*)(d2 + wrOff[nt]) = make_int2((int)lo, (int)hi);
            }
            __syncthreads();                           // tile tt ready
        }
    } else {
        // ========== CONSUMER: L3 + L4 (r13 verbatim, vs2 single-shuffle) ====
        __builtin_amdgcn_s_setprio(1);
        short8 W3A[8][4];
        f32x4  W4c[8];
        #pragma unroll
        for (int nt = 0; nt < 8; ++nt) {
            #pragma unroll
            for (int kk = 0; kk < 4; ++kk) {
                const float* p3 = W3 + (nt * 16 + lm) * HD + kk * 32 + q * 8;
                S8U a3;
                #pragma unroll
                for (int j = 0; j < 4; ++j)
                    a3.u[j] = pk_bf16(p3[2 * j], p3[2 * j + 1]);
                W3A[nt][kk] = a3.s8;
            }
            W4c[nt] = *(const f32x4*)(W4 + nt * 16 + q * 4);
        }
        const float b4v = b4[0];
        const char* b3c = (const char*)b3f;

        #pragma unroll 1
        for (int tt = 0; tt < TPB; ++tt) {
            __syncthreads();                           // wait for tile tt
            const char* s2 = y2x[tt & 1];

            short8 Y2[4];
            #pragma unroll
            for (int kk = 0; kk < 4; ++kk)
                Y2[kk] = *(const short8*)(s2 + rdOff[kk]);
            f32x4 C[8];
            #pragma unroll
            for (int nt = 0; nt < 8; ++nt)
                C[nt] = *(const f32x4*)(b3c + nt * 64 + bIoff);

            #pragma unroll
            for (int kk = 0; kk < 4; ++kk)
                #pragma unroll
                for (int nt = 0; nt < 8; ++nt)
                    C[nt] = __builtin_amdgcn_mfma_f32_16x16x32_bf16(W3A[nt][kk], Y2[kk], C[nt], 0, 0, 0);

            // ---- L4 partial: single shuffle, halves to LDS ----
            float p = 0.f;
            #pragma unroll
            for (int nt = 0; nt < 8; ++nt) {
                p = fmaf(fmaxf(C[nt][0], 0.f), W4c[nt][0], p);
                p = fmaf(fmaxf(C[nt][1], 0.f), W4c[nt][1], p);
                p = fmaf(fmaxf(C[nt][2], 0.f), W4c[nt][2], p);
                p = fmaf(fmaxf(C[nt][3], 0.f), W4c[nt][3], p);
            }
            p += __shfl_xor(p, 32);
            if (lane < 32) vs2[tt * 32 + lane] = p;    // q-group halves
        }

        // ---- deferred epilogue: half-sum + elu + ccw + row-reduce ----
        {
            const int r   = lane >> 2;                 // row 0..15
            const int sub = lane & 3;
            float a = 0.f;
            #pragma unroll 1
            for (int j = 0; j < 13; ++j) {
                int k = sub + 4 * j;
                if (k < KQ) {
                    int s   = r * KQ + k;
                    int tt  = s >> 4;
                    int lm2 = s & 15;
                    float y4 = vs2[tt * 32 + lm2] + vs2[tt * 32 + 16 + lm2] + b4v;
                    float f  = (y4 > 0.f) ? (y4 + 1.f) : __expf(y4);
                    a = fmaf(f, sCcw[k], a);
                }
            }
            a += __shfl_xor(a, 1);
            a += __shfl_xor(a, 2);
            if (sub == 0)
                out[rowBase + r] = a * (xmax - xL[r]) * 0.5f;
        }
    }
}

// ---------------------------------------------------------------------------
extern "C" void kernel_launch(void* const* d_in, const int* in_sizes, int n_in,
                              void* d_out, int out_size, void* d_ws, size_t ws_size,
                              hipStream_t stream)
{
    const float* x  = (const float*)d_in[0];
    const float* h  = (const float*)d_in[1];
    const float* W1 = (const float*)d_in[2];
    const float* b1 = (const float*)d_in[3];
    const float* W2 = (const float*)d_in[4];
    const float* b2 = (const float*)d_in[5];
    const float* W3 = (const float*)d_in[6];
    const float* b3 = (const float*)d_in[7];
    const float* W4 = (const float*)d_in[8];
    const float* b4 = (const float*)d_in[9];
    float* out = (float*)d_out;

    umnn_fused<<<GRID, BLK, 0, stream>>>(x, h, W1, b1, W2, b2, W3, b3,
                                         W4, b4, out);
}

// Round 12
// 169.226 us; speedup vs baseline: 1.1858x; 1.0383x over previous
//
#include <hip/hip_runtime.h>
#include <hip/hip_bf16.h>
#include <math.h>

// ---------------------------------------------------------------------------
// Round 19: r13 (best: 114us) + three register-safe SPAN CUTS.
// Evidence: r12 (+240cyc on C -> +250/phase) and r18 (+~500 on P -> +400)
// show phase ~= max(P,C) + fixed stall; VALUBusy/MfmaUtil cross-check puts
// phase at ~1400-1600 SIMD-cycles with ~60% per-wave stall -- the shaveable
// parts are the known ~100-150cyc serial segments:
//   1. consumer Y2 SOFTWARE PIPELINE: after barrier tt, issue tile tt's 4
//      ds_read_b128; compute tile tt-1 from last phase's regs. Read latency
//      off the chain head. (+16 consumer regs, free: uniform allocation =
//      producer's ~124.) Parity tt&1 rewritten only at tt+2 -> safe.
//   2. consumer C=0-init + bias folded into L4 (relu(C+b3)): removes the 8
//      bias reads gating MFMA kk=0; per-nt b3 reads hide under MFMA drain.
//   3. 4-way split p accumulators (32-deep fmaf chain -> 4x8) + producer
//      C-init hoisted ABOVE the Y1 build (latency under ~300cyc of build).
// Numerics: bias-after-accumulate + split-sum are fp32 reassociations
// (~1e-6); bit-chain otherwise identical to r13. absmax ~0.125.
// ---------------------------------------------------------------------------

#define B_N    16384
#define KQ     51
#define HD     128
#define IND    64
#define BLK    128               // 2 waves: producer + consumer
#define RPB    16                // b-rows per block
#define GRID   (B_N / RPB)       // 1024
#define TPB    ((RPB * KQ) / 16) // 51 tiles per block (exact)

typedef __attribute__((ext_vector_type(8))) short short8;
typedef __attribute__((ext_vector_type(4))) float f32x4;

union S8U { short8 s8; unsigned u[4]; };

__device__ __forceinline__ unsigned short f2bf(float f) {
    __hip_bfloat16 t = __float2bfloat16(f);
    return *reinterpret_cast<unsigned short*>(&t);
}

#if defined(__gfx950__) && defined(__has_builtin)
#if __has_builtin(__builtin_amdgcn_cvt_pk_bf16_f32)
#define HAVE_PK_BF16 1
#endif
#endif

__device__ __forceinline__ unsigned pk_bf16(float lo, float hi) {
#ifdef HAVE_PK_BF16
    typedef __attribute__((ext_vector_type(2))) __bf16 bfv2;
    bfv2 r = __builtin_amdgcn_cvt_pk_bf16_f32(lo, hi);
    return *reinterpret_cast<unsigned*>(&r);
#else
    return (unsigned)f2bf(lo) | ((unsigned)f2bf(hi) << 16);
#endif
}

__launch_bounds__(BLK, 2)
__global__ void umnn_fused(const float* __restrict__ x,  const float* __restrict__ h,
                           const float* __restrict__ W1, const float* __restrict__ b1,
                           const float* __restrict__ W2, const float* __restrict__ b2,
                           const float* __restrict__ W3, const float* __restrict__ b3,
                           const float* __restrict__ W4, const float* __restrict__ b4,
                           float* __restrict__ out)
{
    __shared__ __align__(16) float hpL[RPB * HD];      // 8 KB block hpart
    __shared__ __align__(16) char  y2x[2][4096];       // 8 KB Y2 double buffer
    __shared__ __align__(16) float hshT[63 * 20];      // 5 KB h^T staging
    __shared__ __align__(16) float vs4[TPB * 64];      // 12.75 KB per-lane partials
    __shared__ __align__(16) float b2f[HD], b3f[HD];   // 1 KB fp32 bias tables
    __shared__ float xL[RPB];
    __shared__ float sSteps[KQ], sCcw[KQ];
    __shared__ float red2[2];

    const int tid  = threadIdx.x;
    const int w    = tid >> 6;
    const int lane = tid & 63;
    const int q    = lane >> 4;
    const int lm   = lane & 15;
    const int swz  = lm & 7;
    const int rowBase = blockIdx.x * RPB;

    // ---- CC tables (validated r4 formula) ----
    if (tid < KQ) {
        const int j = tid;
        const float pi50 = 0.06283185307179586f;
        sSteps[j] = __cosf((float)j * pi50);
        float s = 0.0f;
        for (int i = 0; i <= 50; i += 2) {
            float Wi = (i == 0) ? 1.0f : 2.0f / (1.0f - (float)(i * i));
            float lam;
            if (j == 0) lam = 0.5f;
            else {
                int mp = (i * j) % 100;
                lam = __cosf((float)mp * pi50);
                if (j == 50) lam *= 0.5f;
            }
            s += (lam * 0.04f) * Wi;
        }
        sCcw[j] = s;
    }
    // ---- fp32 bias tables ----
    if (tid < HD) {
        b2f[tid] = b2[tid];
        b3f[tid] = b3[tid];
    }
    // ---- xmax scan (x: 64 KB, cache-resident) ----
    {
        const f32x4* x4 = (const f32x4*)x;
        float mx = -1e30f;
        for (int i = tid; i < B_N / 4; i += BLK) {
            f32x4 v = x4[i];
            mx = fmaxf(fmaxf(mx, fmaxf(v[0], v[1])), fmaxf(v[2], v[3]));
        }
        #pragma unroll
        for (int d = 32; d > 0; d >>= 1) mx = fmaxf(mx, __shfl_xor(mx, d));
        if (lane == 0) red2[w] = mx;
    }
    // ---- stage h^T for this block's 16 rows; init xL ----
    for (int i = tid; i < RPB * 63; i += BLK) {
        int r = i / 63, d = i - r * 63;
        hshT[d * 20 + r] = h[rowBase * 63 + i];
    }
    if (tid < RPB) xL[tid] = x[rowBase + tid];
    __syncthreads();                                   // B1

    const float xmax = fmaxf(red2[0], red2[1]) + 10.0f;

    // ---- block hpart: thread tid = feature n, 16 row-accumulators ----
    {
        const int n = tid;
        float acc[RPB];
        const float b1v = b1[n];
        #pragma unroll
        for (int r = 0; r < RPB; ++r) acc[r] = b1v;
        const float* wr = W1 + n * IND + 1;
        #pragma unroll 1
        for (int d = 0; d < IND - 1; ++d) {
            float wv = wr[d];
            const float* ht = hshT + d * 20;
            #pragma unroll
            for (int rc = 0; rc < RPB / 4; ++rc) {
                f32x4 hv = *(const f32x4*)(ht + rc * 4);
                acc[rc * 4 + 0] = fmaf(wv, hv[0], acc[rc * 4 + 0]);
                acc[rc * 4 + 1] = fmaf(wv, hv[1], acc[rc * 4 + 1]);
                acc[rc * 4 + 2] = fmaf(wv, hv[2], acc[rc * 4 + 2]);
                acc[rc * 4 + 3] = fmaf(wv, hv[3], acc[rc * 4 + 3]);
            }
        }
        #pragma unroll
        for (int r = 0; r < RPB; ++r) hpL[r * HD + n] = acc[r];
    }
    __syncthreads();                                   // B2 (hpL ready)

    // per-lane C-init byte offset into bias table: feature nt*16+q*4
    const int bIoff = q * 16;                          // + nt*64 at use site
    int rdOff[4];
    #pragma unroll
    for (int kk = 0; kk < 4; ++kk)
        rdOff[kk] = lm * 256 + (((kk * 4 + q) ^ swz) << 4);

    if (w == 0) {
        // ================= PRODUCER: layer 1 + layer 2 =================
        __builtin_amdgcn_s_setprio(0);
        float w1x[32];
        #pragma unroll
        for (int kk = 0; kk < 4; ++kk)
            #pragma unroll
            for (int j = 0; j < 8; ++j)
                w1x[kk * 8 + j] = W1[(kk * 32 + q * 8 + j) * IND];

        short8 W2A[8][4];
        #pragma unroll
        for (int nt = 0; nt < 8; ++nt) {
            #pragma unroll
            for (int kk = 0; kk < 4; ++kk) {
                const float* p2 = W2 + (nt * 16 + lm) * HD + kk * 32 + q * 8;
                S8U a2;
                #pragma unroll
                for (int j = 0; j < 4; ++j)
                    a2.u[j] = pk_bf16(p2[2 * j], p2[2 * j + 1]);
                W2A[nt][kk] = a2.s8;
            }
        }
        int wrOff[8];
        #pragma unroll
        for (int nt = 0; nt < 8; ++nt)
            wrOff[nt] = lm * 256 + (((2 * nt + (q >> 1)) ^ swz) << 4) + ((q & 1) << 3);
        const char* b2c = (const char*)b2f;

        #pragma unroll 1
        for (int tt = 0; tt < TPB; ++tt) {
            // ---- C-init FIRST: bias-read latency hides under Y1 build ----
            f32x4 C[8];
            #pragma unroll
            for (int nt = 0; nt < 8; ++nt)
                C[nt] = *(const f32x4*)(b2c + nt * 64 + bIoff);

            // ---- layer 1: build Y1 fragment for this tile ----
            const int s    = tt * 16 + lm;             // 0..815
            const unsigned row = (unsigned)s / KQ;     // 0..15
            const int k    = s - (int)row * KQ;
            const float x0 = xL[row];
            const float X  = fmaf((xmax - x0) * 0.5f, sSteps[k] + 1.0f, x0);
            short8 Y1[4];
            #pragma unroll
            for (int kk = 0; kk < 4; ++kk) {
                const float* hp = hpL + row * HD + kk * 32 + q * 8;
                f32x4 ha = *(const f32x4*)hp;
                f32x4 hb = *(const f32x4*)(hp + 4);
                S8U u;
                u.u[0] = pk_bf16(fmaxf(fmaf(X, w1x[kk*8+0], ha[0]), 0.f),
                                 fmaxf(fmaf(X, w1x[kk*8+1], ha[1]), 0.f));
                u.u[1] = pk_bf16(fmaxf(fmaf(X, w1x[kk*8+2], ha[2]), 0.f),
                                 fmaxf(fmaf(X, w1x[kk*8+3], ha[3]), 0.f));
                u.u[2] = pk_bf16(fmaxf(fmaf(X, w1x[kk*8+4], hb[0]), 0.f),
                                 fmaxf(fmaf(X, w1x[kk*8+5], hb[1]), 0.f));
                u.u[3] = pk_bf16(fmaxf(fmaf(X, w1x[kk*8+6], hb[2]), 0.f),
                                 fmaxf(fmaf(X, w1x[kk*8+7], hb[3]), 0.f));
                Y1[kk] = u.s8;
            }

            // ---- layer 2: 32 MFMA ----
            #pragma unroll
            for (int kk = 0; kk < 4; ++kk)
                #pragma unroll
                for (int nt = 0; nt < 8; ++nt)
                    C[nt] = __builtin_amdgcn_mfma_f32_16x16x32_bf16(W2A[nt][kk], Y1[kk], C[nt], 0, 0, 0);

            // ---- relu + pack + write Y2 ----
            char* d2 = y2x[tt & 1];
            #pragma unroll
            for (int nt = 0; nt < 8; ++nt) {
                unsigned lo = pk_bf16(fmaxf(C[nt][0], 0.f), fmaxf(C[nt][1], 0.f));
                unsigned hi = pk_bf16(fmaxf(C[nt][2], 0.f), fmaxf(C[nt][3], 0.f));
                *(int2*)(d2 + wrOff[nt]) = make_int2((int)lo, (int)hi);
            }
            __syncthreads();                           // tile tt ready
        }
    } else {
        // ========= CONSUMER: pipelined layer 3 + layer 4 =========
        __builtin_amdgcn_s_setprio(1);                 // consumer is critical
        short8 W3A[8][4];
        f32x4  W4c[8];
        #pragma unroll
        for (int nt = 0; nt < 8; ++nt) {
            #pragma unroll
            for (int kk = 0; kk < 4; ++kk) {
                const float* p3 = W3 + (nt * 16 + lm) * HD + kk * 32 + q * 8;
                S8U a3;
                #pragma unroll
                for (int j = 0; j < 4; ++j)
                    a3.u[j] = pk_bf16(p3[2 * j], p3[2 * j + 1]);
                W3A[nt][kk] = a3.s8;
            }
            W4c[nt] = *(const f32x4*)(W4 + nt * 16 + q * 4);
        }
        const float b4v = b4[0];
        const char* b3c = (const char*)b3f;

        // full consume body for tile tt using pre-loaded fragments Yp
        auto consume = [&](int tt, const short8* Yp) {
            f32x4 C[8];
            #pragma unroll
            for (int nt = 0; nt < 8; ++nt)
                C[nt] = (f32x4){0.f, 0.f, 0.f, 0.f};   // zero-init: no reads
            #pragma unroll
            for (int kk = 0; kk < 4; ++kk)
                #pragma unroll
                for (int nt = 0; nt < 8; ++nt)
                    C[nt] = __builtin_amdgcn_mfma_f32_16x16x32_bf16(W3A[nt][kk], Yp[kk], C[nt], 0, 0, 0);

            // L4 partial: bias folded here; 4 parallel accumulators
            float p0 = 0.f, p1 = 0.f, p2 = 0.f, p3 = 0.f;
            #pragma unroll
            for (int nt = 0; nt < 8; ++nt) {
                f32x4 bv = *(const f32x4*)(b3c + nt * 64 + bIoff);
                p0 = fmaf(fmaxf(C[nt][0] + bv[0], 0.f), W4c[nt][0], p0);
                p1 = fmaf(fmaxf(C[nt][1] + bv[1], 0.f), W4c[nt][1], p1);
                p2 = fmaf(fmaxf(C[nt][2] + bv[2], 0.f), W4c[nt][2], p2);
                p3 = fmaf(fmaxf(C[nt][3] + bv[3], 0.f), W4c[nt][3], p3);
            }
            vs4[tt * 64 + lane] = (p0 + p1) + (p2 + p3);
        };

        short8 Y2p[4];
        #pragma unroll 1
        for (int tt = 0; tt < TPB; ++tt) {
            __syncthreads();                           // tile tt ready
            const char* s2 = y2x[tt & 1];
            // issue tile tt's reads NOW; latency spans the tt-1 compute
            short8 Y2n[4];
            #pragma unroll
            for (int kk = 0; kk < 4; ++kk)
                Y2n[kk] = *(const short8*)(s2 + rdOff[kk]);

            if (tt > 0) consume(tt - 1, Y2p);

            #pragma unroll
            for (int kk = 0; kk < 4; ++kk) Y2p[kk] = Y2n[kk];
        }
        consume(TPB - 1, Y2p);                         // tail

        // ---- deferred epilogue: 4-way quarter sum + elu + ccw + reduce ----
        {
            const int r   = lane >> 2;                 // row 0..15
            const int sub = lane & 3;
            float a = 0.f;
            #pragma unroll 1
            for (int j = 0; j < 13; ++j) {
                int k = sub + 4 * j;
                if (k < KQ) {
                    int s   = r * KQ + k;
                    int tt  = s >> 4;
                    int lm2 = s & 15;
                    const float* vb = vs4 + tt * 64 + lm2;
                    float y4 = vb[0] + vb[16] + vb[32] + vb[48] + b4v;
                    float f  = (y4 > 0.f) ? (y4 + 1.f) : __expf(y4);
                    a = fmaf(f, sCcw[k], a);
                }
            }
            a += __shfl_xor(a, 1);
            a += __shfl_xor(a, 2);
            if (sub == 0)
                out[rowBase + r] = a * (xmax - xL[r]) * 0.5f;
        }
    }
}

// ---------------------------------------------------------------------------
extern "C" void kernel_launch(void* const* d_in, const int* in_sizes, int n_in,
                              void* d_out, int out_size, void* d_ws, size_t ws_size,
                              hipStream_t stream)
{
    const float* x  = (const float*)d_in[0];
    const float* h  = (const float*)d_in[1];
    const float* W1 = (const float*)d_in[2];
    const float* b1 = (const float*)d_in[3];
    const float* W2 = (const float*)d_in[4];
    const float* b2 = (const float*)d_in[5];
    const float* W3 = (const float*)d_in[6];
    const float* b3 = (const float*)d_in[7];
    const float* W4 = (const float*)d_in[8];
    const float* b4 = (const float*)d_in[9];
    float* out = (float*)d_out;

    umnn_fused<<<GRID, BLK, 0, stream>>>(x, h, W1, b1, W2, b2, W3, b3,
                                         W4, b4, out);
}